// Round 2
// baseline (1126.697 us; speedup 1.0000x reference)
//
#include <hip/hip_runtime.h>
#include <hip/hip_bf16.h>

#define NN 100000
#define NE 6400000

typedef __bf16 bf16x8_t __attribute__((ext_vector_type(8)));
typedef float f32x4_t __attribute__((ext_vector_type(4)));

__device__ __forceinline__ float silu_f(float v) { return v / (1.0f + __expf(-v)); }

// ---------------------------------------------------------------------------
// Node kernel: q[n] = silu( dot( silu(x[n,:]@W1 + b1), W2 ) + b2 )
// fp32 inputs, converted to bf16 for mfma_f32_16x16x32_bf16.
// A[m=lane&15][k=quad*8+j]; B[k=quad*8+j][n=lane&15]; C/D: col=lane&15,
// row=quad*4+reg (verified layouts, learn_hip m89/m91).
// W1 B-fragments register-resident (8 nt x 4 kt x 4 VGPR = 128 VGPRs).
// ---------------------------------------------------------------------------
__global__ __launch_bounds__(256, 2) void node_q_kernel(
    const float* __restrict__ x,
    const float* __restrict__ W1,
    const float* __restrict__ b1,
    const float* __restrict__ W2,
    const float* __restrict__ b2,
    float* __restrict__ q,
    int nGroups)
{
    const int lane = threadIdx.x & 63;
    const int wave = threadIdx.x >> 6;
    const int c    = lane & 15;
    const int quad = lane >> 4;
    const int gwave  = blockIdx.x * 4 + wave;
    const int nWaves = gridDim.x * 4;

    bf16x8_t bfrag[8][4];
    float b1v[8], w2v[8];
#pragma unroll
    for (int nt = 0; nt < 8; ++nt) {
        const int n = nt * 16 + c;
#pragma unroll
        for (int kt = 0; kt < 4; ++kt) {
            const float* p = W1 + (kt * 32 + quad * 8) * 128 + n;
#pragma unroll
            for (int j = 0; j < 8; ++j)
                bfrag[nt][kt][j] = (__bf16)p[j * 128];
        }
        b1v[nt] = b1[n];
        w2v[nt] = W2[n];
    }
    const float b2v = b2[0];

    for (int g = gwave; g < nGroups; g += nWaves) {
        const float* xrow = x + (size_t)(g * 16 + c) * 128 + quad * 8;
        bf16x8_t afrag[4];
#pragma unroll
        for (int kt = 0; kt < 4; ++kt) {
            const f32x4_t x0 = *reinterpret_cast<const f32x4_t*>(xrow + kt * 32);
            const f32x4_t x1 = *reinterpret_cast<const f32x4_t*>(xrow + kt * 32 + 4);
#pragma unroll
            for (int j = 0; j < 4; ++j) {
                afrag[kt][j]     = (__bf16)x0[j];
                afrag[kt][j + 4] = (__bf16)x1[j];
            }
        }

        float cr[4] = {0.f, 0.f, 0.f, 0.f};
#pragma unroll
        for (int nt = 0; nt < 8; ++nt) {
            f32x4_t acc = {0.f, 0.f, 0.f, 0.f};
#pragma unroll
            for (int kt = 0; kt < 4; ++kt)
                acc = __builtin_amdgcn_mfma_f32_16x16x32_bf16(afrag[kt], bfrag[nt][kt], acc, 0, 0, 0);
#pragma unroll
            for (int r = 0; r < 4; ++r)
                cr[r] += silu_f(acc[r] + b1v[nt]) * w2v[nt];
        }
        // sum the 16 column-lanes within each quad (nt loop covered all 128 cols)
#pragma unroll
        for (int r = 0; r < 4; ++r) {
            float v = cr[r];
            v += __shfl_xor(v, 1);
            v += __shfl_xor(v, 2);
            v += __shfl_xor(v, 4);
            v += __shfl_xor(v, 8);
            cr[r] = v;
        }
        if (c == 0) {
#pragma unroll
            for (int r = 0; r < 4; ++r)
                q[g * 16 + quad * 4 + r] = silu_f(cr[r] + b2v);
        }
    }
}

// ---------------------------------------------------------------------------
// Edge kernel: mu[dst] += vij * q[src] * cutoff(rij). 4 edges per thread,
// float4/int4 coalesced loads; fp32 atomics into d_out.
// ---------------------------------------------------------------------------
__global__ __launch_bounds__(256) void edge_kernel(
    const float4* __restrict__ rij4,
    const float4* __restrict__ vij4,
    const int4* __restrict__ src4,
    const int4* __restrict__ dst4,
    const float* __restrict__ q,
    float* __restrict__ mu)
{
    const int t = blockIdx.x * 256 + threadIdx.x;   // t < NE/4 exactly
    const int4 s = src4[t];
    const int4 d = dst4[t];
    const float4 r = rij4[t];
    const float4 v0 = vij4[3 * t + 0];   // e0.x e0.y e0.z e1.x
    const float4 v1 = vij4[3 * t + 1];   // e1.y e1.z e2.x e2.y
    const float4 v2 = vij4[3 * t + 2];   // e2.z e3.x e3.y e3.z

    const float K = 0.62831853071795864769f;  // pi / 5
    const float c0 = (r.x < 5.0f) ? 0.5f * (__cosf(r.x * K) + 1.0f) : 0.0f;
    const float c1 = (r.y < 5.0f) ? 0.5f * (__cosf(r.y * K) + 1.0f) : 0.0f;
    const float c2 = (r.z < 5.0f) ? 0.5f * (__cosf(r.z * K) + 1.0f) : 0.0f;
    const float c3 = (r.w < 5.0f) ? 0.5f * (__cosf(r.w * K) + 1.0f) : 0.0f;

    const float s0 = q[s.x] * c0;
    const float s1 = q[s.y] * c1;
    const float s2 = q[s.z] * c2;
    const float s3 = q[s.w] * c3;

    float* m0 = mu + 3 * (size_t)d.x;
    atomicAdd(m0 + 0, v0.x * s0);
    atomicAdd(m0 + 1, v0.y * s0);
    atomicAdd(m0 + 2, v0.z * s0);
    float* m1 = mu + 3 * (size_t)d.y;
    atomicAdd(m1 + 0, v0.w * s1);
    atomicAdd(m1 + 1, v1.x * s1);
    atomicAdd(m1 + 2, v1.y * s1);
    float* m2 = mu + 3 * (size_t)d.z;
    atomicAdd(m2 + 0, v1.z * s2);
    atomicAdd(m2 + 1, v1.w * s2);
    atomicAdd(m2 + 2, v2.x * s2);
    float* m3 = mu + 3 * (size_t)d.w;
    atomicAdd(m3 + 0, v2.y * s3);
    atomicAdd(m3 + 1, v2.z * s3);
    atomicAdd(m3 + 2, v2.w * s3);
}

extern "C" void kernel_launch(void* const* d_in, const int* in_sizes, int n_in,
                              void* d_out, int out_size, void* d_ws, size_t ws_size,
                              hipStream_t stream)
{
    const float* x   = (const float*)d_in[0];
    const float* rij = (const float*)d_in[1];
    const float* vij = (const float*)d_in[2];
    const int*   src = (const int*)d_in[3];
    const int*   dst = (const int*)d_in[4];
    const float* W1  = (const float*)d_in[5];
    const float* b1  = (const float*)d_in[6];
    const float* W2  = (const float*)d_in[7];
    const float* b2  = (const float*)d_in[8];

    float* mu = (float*)d_out;      // accumulate directly into output (fp32)
    float* q  = (float*)d_ws;       // NN fp32 node scalars

    hipMemsetAsync(mu, 0, (size_t)NN * 3 * sizeof(float), stream);

    node_q_kernel<<<256, 256, 0, stream>>>(x, W1, b1, W2, b2, q, NN / 16);

    edge_kernel<<<NE / 4 / 256, 256, 0, stream>>>(
        (const float4*)rij, (const float4*)vij, (const int4*)src, (const int4*)dst, q, mu);
}

// Round 3
// 424.687 us; speedup vs baseline: 2.6530x; 2.6530x over previous
//
#include <hip/hip_runtime.h>
#include <hip/hip_bf16.h>

#define NN 100000
#define NE 6400000
#define S_SLICES 20
#define SLICE 5000              // NN / S_SLICES nodes per slice
#define SLICE_F (SLICE * 3)     // 15000 floats per slice accumulator
#define CAP 336000              // arena capacity per slice (mean 320K + 29 sigma)
#define NB1 250                 // pass-1 blocks
#define CHUNK (NE / NB1)        // 25600 edges per pass-1 block
#define C2 26                   // pass-2 blocks per slice

typedef __bf16 bf16x8_t __attribute__((ext_vector_type(8)));
typedef float f32x4_t __attribute__((ext_vector_type(4)));

__device__ __forceinline__ float silu_f(float v) { return v / (1.0f + __expf(-v)); }

// ---------------------------------------------------------------------------
// Node kernel: q[n] = silu( dot( silu(x[n,:]@W1 + b1), W2 ) + b2 )
// fp32 inputs -> bf16 for mfma_f32_16x16x32_bf16 (verified layouts m89/m91).
// W1 B-fragments register-resident (8 nt x 4 kt x 4 VGPR = 128 VGPRs).
// grid=512: 2048 waves (~8/CU) to hide x-load latency.
// ---------------------------------------------------------------------------
__global__ __launch_bounds__(256, 2) void node_q_kernel(
    const float* __restrict__ x,
    const float* __restrict__ W1,
    const float* __restrict__ b1,
    const float* __restrict__ W2,
    const float* __restrict__ b2,
    float* __restrict__ q,
    int nGroups)
{
    const int lane = threadIdx.x & 63;
    const int wave = threadIdx.x >> 6;
    const int c    = lane & 15;
    const int quad = lane >> 4;
    const int gwave  = blockIdx.x * 4 + wave;
    const int nWaves = gridDim.x * 4;

    bf16x8_t bfrag[8][4];
    float b1v[8], w2v[8];
#pragma unroll
    for (int nt = 0; nt < 8; ++nt) {
        const int n = nt * 16 + c;
#pragma unroll
        for (int kt = 0; kt < 4; ++kt) {
            const float* p = W1 + (kt * 32 + quad * 8) * 128 + n;
#pragma unroll
            for (int j = 0; j < 8; ++j)
                bfrag[nt][kt][j] = (__bf16)p[j * 128];
        }
        b1v[nt] = b1[n];
        w2v[nt] = W2[n];
    }
    const float b2v = b2[0];

    for (int g = gwave; g < nGroups; g += nWaves) {
        const float* xrow = x + (size_t)(g * 16 + c) * 128 + quad * 8;
        bf16x8_t afrag[4];
#pragma unroll
        for (int kt = 0; kt < 4; ++kt) {
            const f32x4_t x0 = *reinterpret_cast<const f32x4_t*>(xrow + kt * 32);
            const f32x4_t x1 = *reinterpret_cast<const f32x4_t*>(xrow + kt * 32 + 4);
#pragma unroll
            for (int j = 0; j < 4; ++j) {
                afrag[kt][j]     = (__bf16)x0[j];
                afrag[kt][j + 4] = (__bf16)x1[j];
            }
        }

        float cr[4] = {0.f, 0.f, 0.f, 0.f};
#pragma unroll
        for (int nt = 0; nt < 8; ++nt) {
            f32x4_t acc = {0.f, 0.f, 0.f, 0.f};
#pragma unroll
            for (int kt = 0; kt < 4; ++kt)
                acc = __builtin_amdgcn_mfma_f32_16x16x32_bf16(afrag[kt], bfrag[nt][kt], acc, 0, 0, 0);
#pragma unroll
            for (int r = 0; r < 4; ++r)
                cr[r] += silu_f(acc[r] + b1v[nt]) * w2v[nt];
        }
#pragma unroll
        for (int r = 0; r < 4; ++r) {
            float v = cr[r];
            v += __shfl_xor(v, 1);
            v += __shfl_xor(v, 2);
            v += __shfl_xor(v, 4);
            v += __shfl_xor(v, 8);
            cr[r] = v;
        }
        if (c == 0) {
#pragma unroll
            for (int r = 0; r < 4; ++r)
                q[g * 16 + quad * 4 + r] = silu_f(cr[r] + b2v);
        }
    }
}

// ---------------------------------------------------------------------------
// Pass 1: bucket edges by dst-slice into dense per-slice arenas.
// Record = {dst_local:int, w*vx, w*vy, w*vz} (16 B), w = q[src]*cutoff(rij).
// Only 20 global int atomics per block for arena reservation.
// ---------------------------------------------------------------------------
__device__ __forceinline__ void emit_rec(int d, float w, float vx, float vy, float vz,
                                         int* lcnt, const int* base, int4* arena)
{
    const int s = d / SLICE;
    const int rank = atomicAdd(&lcnt[s], 1);
    const int pos = base[s] + rank;
    int4 rec;
    rec.x = d - s * SLICE;
    rec.y = __float_as_int(vx * w);
    rec.z = __float_as_int(vy * w);
    rec.w = __float_as_int(vz * w);
    arena[(size_t)s * CAP + pos] = rec;
}

__global__ __launch_bounds__(256) void bucket_kernel(
    const float4* __restrict__ rij4,
    const float4* __restrict__ vij4,
    const int4* __restrict__ src4,
    const int4* __restrict__ dst4,
    const float* __restrict__ q,
    int* __restrict__ gcnt,
    int4* __restrict__ arena)
{
    __shared__ int hist[S_SLICES];
    __shared__ int base[S_SLICES];
    __shared__ int lcnt[S_SLICES];
    const int t = threadIdx.x;
    if (t < S_SLICES) { hist[t] = 0; lcnt[t] = 0; }
    __syncthreads();

    const int g4 = blockIdx.x * (CHUNK / 4);    // first int4-group of this chunk

    // Phase A: per-slice histogram (dst only; chunk stays L1/L2-hot for B)
#pragma unroll 5
    for (int i = 0; i < CHUNK / 4 / 256; ++i) { // 25 iters
        const int4 d = dst4[g4 + i * 256 + t];
        atomicAdd(&hist[d.x / SLICE], 1);
        atomicAdd(&hist[d.y / SLICE], 1);
        atomicAdd(&hist[d.z / SLICE], 1);
        atomicAdd(&hist[d.w / SLICE], 1);
    }
    __syncthreads();
    if (t < S_SLICES) base[t] = atomicAdd(&gcnt[t], hist[t]);
    __syncthreads();

    // Phase B: compute premultiplied records, scatter into reserved arena space
    const float K = 0.62831853071795864769f;    // pi / 5
    for (int i = 0; i < CHUNK / 4 / 256; ++i) {
        const int idx = g4 + i * 256 + t;
        const int4 s = src4[idx];
        const int4 d = dst4[idx];
        const float4 r = rij4[idx];
        const float4 v0 = vij4[3 * idx + 0];    // e0.x e0.y e0.z e1.x
        const float4 v1 = vij4[3 * idx + 1];    // e1.y e1.z e2.x e2.y
        const float4 v2 = vij4[3 * idx + 2];    // e2.z e3.x e3.y e3.z

        const float c0 = (r.x < 5.0f) ? 0.5f * (__cosf(r.x * K) + 1.0f) : 0.0f;
        const float c1 = (r.y < 5.0f) ? 0.5f * (__cosf(r.y * K) + 1.0f) : 0.0f;
        const float c2 = (r.z < 5.0f) ? 0.5f * (__cosf(r.z * K) + 1.0f) : 0.0f;
        const float c3 = (r.w < 5.0f) ? 0.5f * (__cosf(r.w * K) + 1.0f) : 0.0f;

        emit_rec(d.x, q[s.x] * c0, v0.x, v0.y, v0.z, lcnt, base, arena);
        emit_rec(d.y, q[s.y] * c1, v0.w, v1.x, v1.y, lcnt, base, arena);
        emit_rec(d.z, q[s.z] * c2, v1.z, v1.w, v2.x, lcnt, base, arena);
        emit_rec(d.w, q[s.w] * c3, v2.y, v2.z, v2.w, lcnt, base, arena);
    }
}

// ---------------------------------------------------------------------------
// Pass 2: each block reduces a 1/C2 chunk of one slice's records into a
// 60 KB LDS accumulator (LDS float atomics; random dst order => low conflict),
// then streams the partial out.
// ---------------------------------------------------------------------------
__global__ __launch_bounds__(256) void slice_reduce_kernel(
    const int4* __restrict__ arena,
    const int* __restrict__ gcnt,
    float* __restrict__ part)
{
    __shared__ float acc[SLICE_F];              // 60000 B
    const int s = blockIdx.x / C2;
    const int c = blockIdx.x % C2;

    for (int i = threadIdx.x; i < SLICE_F; i += 256) acc[i] = 0.f;
    __syncthreads();

    const int n = gcnt[s];
    const int4* a = arena + (size_t)s * CAP;
    for (int i = c * 256 + threadIdx.x; i < n; i += C2 * 256) {
        const int4 rec = a[i];
        float* p = &acc[rec.x * 3];
        atomicAdd(p + 0, __int_as_float(rec.y));
        atomicAdd(p + 1, __int_as_float(rec.z));
        atomicAdd(p + 2, __int_as_float(rec.w));
    }
    __syncthreads();

    float* dp = part + (size_t)blockIdx.x * SLICE_F;
    for (int i = threadIdx.x; i < SLICE_F; i += 256) dp[i] = acc[i];
}

// ---------------------------------------------------------------------------
// Pass 3: sum the C2 partials per slice into the fp32 output.
// ---------------------------------------------------------------------------
__global__ __launch_bounds__(256) void finalize_kernel(
    const float* __restrict__ part,
    float* __restrict__ out)
{
    const int i = blockIdx.x * 256 + threadIdx.x;
    if (i >= NN * 3) return;
    const int s = i / SLICE_F;
    const int loc = i - s * SLICE_F;
    const float* p = part + ((size_t)s * C2) * SLICE_F + loc;
    float sum = 0.f;
#pragma unroll
    for (int c = 0; c < C2; ++c) sum += p[(size_t)c * SLICE_F];
    out[i] = sum;
}

// ---------------------------------------------------------------------------
// Fallback (small ws): round-2 atomic scatter
// ---------------------------------------------------------------------------
__global__ __launch_bounds__(256) void edge_atomic_kernel(
    const float4* __restrict__ rij4,
    const float4* __restrict__ vij4,
    const int4* __restrict__ src4,
    const int4* __restrict__ dst4,
    const float* __restrict__ q,
    float* __restrict__ mu)
{
    const int t = blockIdx.x * 256 + threadIdx.x;
    const int4 s = src4[t];
    const int4 d = dst4[t];
    const float4 r = rij4[t];
    const float4 v0 = vij4[3 * t + 0];
    const float4 v1 = vij4[3 * t + 1];
    const float4 v2 = vij4[3 * t + 2];
    const float K = 0.62831853071795864769f;
    const float c0 = (r.x < 5.0f) ? 0.5f * (__cosf(r.x * K) + 1.0f) : 0.0f;
    const float c1 = (r.y < 5.0f) ? 0.5f * (__cosf(r.y * K) + 1.0f) : 0.0f;
    const float c2 = (r.z < 5.0f) ? 0.5f * (__cosf(r.z * K) + 1.0f) : 0.0f;
    const float c3 = (r.w < 5.0f) ? 0.5f * (__cosf(r.w * K) + 1.0f) : 0.0f;
    const float s0 = q[s.x] * c0, s1 = q[s.y] * c1, s2 = q[s.z] * c2, s3 = q[s.w] * c3;
    float* m0 = mu + 3 * (size_t)d.x;
    atomicAdd(m0 + 0, v0.x * s0); atomicAdd(m0 + 1, v0.y * s0); atomicAdd(m0 + 2, v0.z * s0);
    float* m1 = mu + 3 * (size_t)d.y;
    atomicAdd(m1 + 0, v0.w * s1); atomicAdd(m1 + 1, v1.x * s1); atomicAdd(m1 + 2, v1.y * s1);
    float* m2 = mu + 3 * (size_t)d.z;
    atomicAdd(m2 + 0, v1.z * s2); atomicAdd(m2 + 1, v1.w * s2); atomicAdd(m2 + 2, v2.x * s2);
    float* m3 = mu + 3 * (size_t)d.w;
    atomicAdd(m3 + 0, v2.y * s3); atomicAdd(m3 + 1, v2.z * s3); atomicAdd(m3 + 2, v2.w * s3);
}

extern "C" void kernel_launch(void* const* d_in, const int* in_sizes, int n_in,
                              void* d_out, int out_size, void* d_ws, size_t ws_size,
                              hipStream_t stream)
{
    const float* x   = (const float*)d_in[0];
    const float* rij = (const float*)d_in[1];
    const float* vij = (const float*)d_in[2];
    const int*   src = (const int*)d_in[3];
    const int*   dst = (const int*)d_in[4];
    const float* W1  = (const float*)d_in[5];
    const float* b1  = (const float*)d_in[6];
    const float* W2  = (const float*)d_in[7];
    const float* b2  = (const float*)d_in[8];

    char* ws = (char*)d_ws;
    const size_t Q_OFF    = 0;                                   // 400 KB
    const size_t CNT_OFF  = 400000;                              // 80 B
    const size_t REC_OFF  = 1048576;                             // arenas: 20*CAP*16 B
    const size_t PART_OFF = REC_OFF + (size_t)S_SLICES * CAP * 16;
    const size_t WS_NEEDED = PART_OFF + (size_t)S_SLICES * C2 * SLICE_F * 4;

    float* q = (float*)(ws + Q_OFF);

    node_q_kernel<<<512, 256, 0, stream>>>(x, W1, b1, W2, b2, q, NN / 16);

    if (ws_size >= WS_NEEDED) {
        int*   gcnt  = (int*)(ws + CNT_OFF);
        int4*  arena = (int4*)(ws + REC_OFF);
        float* part  = (float*)(ws + PART_OFF);

        hipMemsetAsync(gcnt, 0, S_SLICES * sizeof(int), stream);
        bucket_kernel<<<NB1, 256, 0, stream>>>(
            (const float4*)rij, (const float4*)vij, (const int4*)src, (const int4*)dst,
            q, gcnt, arena);
        slice_reduce_kernel<<<S_SLICES * C2, 256, 0, stream>>>(arena, gcnt, part);
        finalize_kernel<<<(NN * 3 + 255) / 256, 256, 0, stream>>>(part, (float*)d_out);
    } else {
        hipMemsetAsync(d_out, 0, (size_t)NN * 3 * sizeof(float), stream);
        edge_atomic_kernel<<<NE / 4 / 256, 256, 0, stream>>>(
            (const float4*)rij, (const float4*)vij, (const int4*)src, (const int4*)dst,
            q, (float*)d_out);
    }
}

// Round 4
// 393.740 us; speedup vs baseline: 2.8615x; 1.0786x over previous
//
#include <hip/hip_runtime.h>
#include <hip/hip_bf16.h>

#define NN 100000
#define NE 6400000
#define S_SLICES 40
#define SLICE 2500              // NN / S_SLICES nodes per slice
#define SLICE_F (SLICE * 3)     // 7500 floats per slice accumulator (30 KB)
#define CAP 166000              // arena capacity per slice (mean 160K + ~15 sigma)
#define NB1 250                 // pass-1 blocks
#define CHUNK (NE / NB1)        // 25600 edges per pass-1 block
#define C2 24                   // pass-2 blocks per slice (960 blocks total)

typedef __bf16 bf16x8_t __attribute__((ext_vector_type(8)));
typedef float f32x4_t __attribute__((ext_vector_type(4)));

__device__ __forceinline__ float silu_f(float v) { return v / (1.0f + __expf(-v)); }

// ---------------------------------------------------------------------------
// Node kernel: q[n] = silu( dot( silu(x[n,:]@W1 + b1), W2 ) + b2 )
// fp32 inputs -> bf16 for mfma_f32_16x16x32_bf16 (verified layouts m89/m91).
// W1 B-fragments register-resident (8 nt x 4 kt x 4 VGPR = 128 VGPRs).
// ---------------------------------------------------------------------------
__global__ __launch_bounds__(256, 2) void node_q_kernel(
    const float* __restrict__ x,
    const float* __restrict__ W1,
    const float* __restrict__ b1,
    const float* __restrict__ W2,
    const float* __restrict__ b2,
    float* __restrict__ q,
    int nGroups)
{
    const int lane = threadIdx.x & 63;
    const int wave = threadIdx.x >> 6;
    const int c    = lane & 15;
    const int quad = lane >> 4;
    const int gwave  = blockIdx.x * 4 + wave;
    const int nWaves = gridDim.x * 4;

    bf16x8_t bfrag[8][4];
    float b1v[8], w2v[8];
#pragma unroll
    for (int nt = 0; nt < 8; ++nt) {
        const int n = nt * 16 + c;
#pragma unroll
        for (int kt = 0; kt < 4; ++kt) {
            const float* p = W1 + (kt * 32 + quad * 8) * 128 + n;
#pragma unroll
            for (int j = 0; j < 8; ++j)
                bfrag[nt][kt][j] = (__bf16)p[j * 128];
        }
        b1v[nt] = b1[n];
        w2v[nt] = W2[n];
    }
    const float b2v = b2[0];

    for (int g = gwave; g < nGroups; g += nWaves) {
        const float* xrow = x + (size_t)(g * 16 + c) * 128 + quad * 8;
        bf16x8_t afrag[4];
#pragma unroll
        for (int kt = 0; kt < 4; ++kt) {
            const f32x4_t x0 = *reinterpret_cast<const f32x4_t*>(xrow + kt * 32);
            const f32x4_t x1 = *reinterpret_cast<const f32x4_t*>(xrow + kt * 32 + 4);
#pragma unroll
            for (int j = 0; j < 4; ++j) {
                afrag[kt][j]     = (__bf16)x0[j];
                afrag[kt][j + 4] = (__bf16)x1[j];
            }
        }

        float cr[4] = {0.f, 0.f, 0.f, 0.f};
#pragma unroll
        for (int nt = 0; nt < 8; ++nt) {
            f32x4_t acc = {0.f, 0.f, 0.f, 0.f};
#pragma unroll
            for (int kt = 0; kt < 4; ++kt)
                acc = __builtin_amdgcn_mfma_f32_16x16x32_bf16(afrag[kt], bfrag[nt][kt], acc, 0, 0, 0);
#pragma unroll
            for (int r = 0; r < 4; ++r)
                cr[r] += silu_f(acc[r] + b1v[nt]) * w2v[nt];
        }
#pragma unroll
        for (int r = 0; r < 4; ++r) {
            float v = cr[r];
            v += __shfl_xor(v, 1);
            v += __shfl_xor(v, 2);
            v += __shfl_xor(v, 4);
            v += __shfl_xor(v, 8);
            cr[r] = v;
        }
        if (c == 0) {
#pragma unroll
            for (int r = 0; r < 4; ++r)
                q[g * 16 + quad * 4 + r] = silu_f(cr[r] + b2v);
        }
    }
}

// ---------------------------------------------------------------------------
// Pass 1: bucket edges by dst-slice into dense per-slice arenas.
// Record = {dst_local:int, w*vx, w*vy, w*vz} (16 B), w = q[src]*cutoff(rij).
// Per-wave histograms in phase A to cut same-address LDS atomic contention.
// ---------------------------------------------------------------------------
__device__ __forceinline__ void emit_rec(int d, float w, float vx, float vy, float vz,
                                         int* lcnt, const int* base, int4* arena)
{
    const int s = d / SLICE;
    const int rank = atomicAdd(&lcnt[s], 1);
    const int pos = base[s] + rank;
    int4 rec;
    rec.x = d - s * SLICE;
    rec.y = __float_as_int(vx * w);
    rec.z = __float_as_int(vy * w);
    rec.w = __float_as_int(vz * w);
    arena[(size_t)s * CAP + pos] = rec;
}

__global__ __launch_bounds__(256) void bucket_kernel(
    const float4* __restrict__ rij4,
    const float4* __restrict__ vij4,
    const int4* __restrict__ src4,
    const int4* __restrict__ dst4,
    const float* __restrict__ q,
    int* __restrict__ gcnt,
    int4* __restrict__ arena)
{
    __shared__ int hist[4][S_SLICES];
    __shared__ int base[S_SLICES];
    __shared__ int lcnt[S_SLICES];
    const int t = threadIdx.x;
    const int w = t >> 6;
    if (t < 4 * S_SLICES) ((int*)hist)[t] = 0;
    if (t < S_SLICES) lcnt[t] = 0;
    __syncthreads();

    const int g4 = blockIdx.x * (CHUNK / 4);    // first int4-group of this chunk

    // Phase A: per-slice histogram (per-wave counters, combined after)
#pragma unroll 5
    for (int i = 0; i < CHUNK / 4 / 256; ++i) { // 25 iters
        const int4 d = dst4[g4 + i * 256 + t];
        atomicAdd(&hist[w][d.x / SLICE], 1);
        atomicAdd(&hist[w][d.y / SLICE], 1);
        atomicAdd(&hist[w][d.z / SLICE], 1);
        atomicAdd(&hist[w][d.w / SLICE], 1);
    }
    __syncthreads();
    if (t < S_SLICES) {
        const int h = hist[0][t] + hist[1][t] + hist[2][t] + hist[3][t];
        base[t] = atomicAdd(&gcnt[t], h);
    }
    __syncthreads();

    // Phase B: premultiplied records scattered into reserved arena space
    const float K = 0.62831853071795864769f;    // pi / 5
    for (int i = 0; i < CHUNK / 4 / 256; ++i) {
        const int idx = g4 + i * 256 + t;
        const int4 s = src4[idx];
        const int4 d = dst4[idx];
        const float4 r = rij4[idx];
        const float4 v0 = vij4[3 * idx + 0];    // e0.x e0.y e0.z e1.x
        const float4 v1 = vij4[3 * idx + 1];    // e1.y e1.z e2.x e2.y
        const float4 v2 = vij4[3 * idx + 2];    // e2.z e3.x e3.y e3.z

        const float c0 = (r.x < 5.0f) ? 0.5f * (__cosf(r.x * K) + 1.0f) : 0.0f;
        const float c1 = (r.y < 5.0f) ? 0.5f * (__cosf(r.y * K) + 1.0f) : 0.0f;
        const float c2 = (r.z < 5.0f) ? 0.5f * (__cosf(r.z * K) + 1.0f) : 0.0f;
        const float c3 = (r.w < 5.0f) ? 0.5f * (__cosf(r.w * K) + 1.0f) : 0.0f;

        emit_rec(d.x, q[s.x] * c0, v0.x, v0.y, v0.z, lcnt, base, arena);
        emit_rec(d.y, q[s.y] * c1, v0.w, v1.x, v1.y, lcnt, base, arena);
        emit_rec(d.z, q[s.z] * c2, v1.z, v1.w, v2.x, lcnt, base, arena);
        emit_rec(d.w, q[s.w] * c3, v2.y, v2.z, v2.w, lcnt, base, arena);
    }
}

// ---------------------------------------------------------------------------
// Pass 2: each block reduces a 1/C2 chunk of one slice's records into a
// 30 KB LDS accumulator. Batch-4 record loads (64 B/thread) for MLP;
// LDS float atomics (random dst => ~2-way banking, free).
// ---------------------------------------------------------------------------
__global__ __launch_bounds__(256) void slice_reduce_kernel(
    const int4* __restrict__ arena,
    const int* __restrict__ gcnt,
    float* __restrict__ part)
{
    __shared__ float acc[SLICE_F];              // 30000 B
    const int s = blockIdx.x / C2;
    const int c = blockIdx.x % C2;

    for (int i = threadIdx.x; i < SLICE_F; i += 256) acc[i] = 0.f;
    __syncthreads();

    const int n = gcnt[s];
    const int4* a = arena + (size_t)s * CAP;
    const int stride = C2 * 256 * 4;
    for (int i0 = (c * 256 + threadIdx.x) * 4; i0 < n; i0 += stride) {
        const int cnt = min(4, n - i0);
        int4 r[4];
#pragma unroll
        for (int k = 0; k < 4; ++k)
            if (k < cnt) r[k] = a[i0 + k];
#pragma unroll
        for (int k = 0; k < 4; ++k)
            if (k < cnt) {
                float* p = &acc[r[k].x * 3];
                atomicAdd(p + 0, __int_as_float(r[k].y));
                atomicAdd(p + 1, __int_as_float(r[k].z));
                atomicAdd(p + 2, __int_as_float(r[k].w));
            }
    }
    __syncthreads();

    float* dp = part + (size_t)blockIdx.x * SLICE_F;
    for (int i = threadIdx.x; i < SLICE_F; i += 256) dp[i] = acc[i];
}

// ---------------------------------------------------------------------------
// Pass 3: sum the C2 partials per slice into the fp32 output.
// ---------------------------------------------------------------------------
__global__ __launch_bounds__(256) void finalize_kernel(
    const float* __restrict__ part,
    float* __restrict__ out)
{
    const int i = blockIdx.x * 256 + threadIdx.x;
    if (i >= NN * 3) return;
    const int s = i / SLICE_F;
    const int loc = i - s * SLICE_F;
    const float* p = part + ((size_t)s * C2) * SLICE_F + loc;
    float sum = 0.f;
#pragma unroll
    for (int c = 0; c < C2; ++c) sum += p[(size_t)c * SLICE_F];
    out[i] = sum;
}

// ---------------------------------------------------------------------------
// Fallback (small ws): atomic scatter
// ---------------------------------------------------------------------------
__global__ __launch_bounds__(256) void edge_atomic_kernel(
    const float4* __restrict__ rij4,
    const float4* __restrict__ vij4,
    const int4* __restrict__ src4,
    const int4* __restrict__ dst4,
    const float* __restrict__ q,
    float* __restrict__ mu)
{
    const int t = blockIdx.x * 256 + threadIdx.x;
    const int4 s = src4[t];
    const int4 d = dst4[t];
    const float4 r = rij4[t];
    const float4 v0 = vij4[3 * t + 0];
    const float4 v1 = vij4[3 * t + 1];
    const float4 v2 = vij4[3 * t + 2];
    const float K = 0.62831853071795864769f;
    const float c0 = (r.x < 5.0f) ? 0.5f * (__cosf(r.x * K) + 1.0f) : 0.0f;
    const float c1 = (r.y < 5.0f) ? 0.5f * (__cosf(r.y * K) + 1.0f) : 0.0f;
    const float c2 = (r.z < 5.0f) ? 0.5f * (__cosf(r.z * K) + 1.0f) : 0.0f;
    const float c3 = (r.w < 5.0f) ? 0.5f * (__cosf(r.w * K) + 1.0f) : 0.0f;
    const float s0 = q[s.x] * c0, s1 = q[s.y] * c1, s2 = q[s.z] * c2, s3 = q[s.w] * c3;
    float* m0 = mu + 3 * (size_t)d.x;
    atomicAdd(m0 + 0, v0.x * s0); atomicAdd(m0 + 1, v0.y * s0); atomicAdd(m0 + 2, v0.z * s0);
    float* m1 = mu + 3 * (size_t)d.y;
    atomicAdd(m1 + 0, v0.w * s1); atomicAdd(m1 + 1, v1.x * s1); atomicAdd(m1 + 2, v1.y * s1);
    float* m2 = mu + 3 * (size_t)d.z;
    atomicAdd(m2 + 0, v1.z * s2); atomicAdd(m2 + 1, v1.w * s2); atomicAdd(m2 + 2, v2.x * s2);
    float* m3 = mu + 3 * (size_t)d.w;
    atomicAdd(m3 + 0, v2.y * s3); atomicAdd(m3 + 1, v2.z * s3); atomicAdd(m3 + 2, v2.w * s3);
}

extern "C" void kernel_launch(void* const* d_in, const int* in_sizes, int n_in,
                              void* d_out, int out_size, void* d_ws, size_t ws_size,
                              hipStream_t stream)
{
    const float* x   = (const float*)d_in[0];
    const float* rij = (const float*)d_in[1];
    const float* vij = (const float*)d_in[2];
    const int*   src = (const int*)d_in[3];
    const int*   dst = (const int*)d_in[4];
    const float* W1  = (const float*)d_in[5];
    const float* b1  = (const float*)d_in[6];
    const float* W2  = (const float*)d_in[7];
    const float* b2  = (const float*)d_in[8];

    char* ws = (char*)d_ws;
    const size_t Q_OFF    = 0;                                   // 400 KB
    const size_t CNT_OFF  = 400000;                              // 160 B
    const size_t REC_OFF  = 1048576;                             // arenas: 40*CAP*16 B
    const size_t PART_OFF = REC_OFF + (size_t)S_SLICES * CAP * 16;
    const size_t WS_NEEDED = PART_OFF + (size_t)S_SLICES * C2 * SLICE_F * 4;  // ~136 MB

    float* q = (float*)(ws + Q_OFF);

    node_q_kernel<<<512, 256, 0, stream>>>(x, W1, b1, W2, b2, q, NN / 16);

    if (ws_size >= WS_NEEDED) {
        int*   gcnt  = (int*)(ws + CNT_OFF);
        int4*  arena = (int4*)(ws + REC_OFF);
        float* part  = (float*)(ws + PART_OFF);

        hipMemsetAsync(gcnt, 0, S_SLICES * sizeof(int), stream);
        bucket_kernel<<<NB1, 256, 0, stream>>>(
            (const float4*)rij, (const float4*)vij, (const int4*)src, (const int4*)dst,
            q, gcnt, arena);
        slice_reduce_kernel<<<S_SLICES * C2, 256, 0, stream>>>(arena, gcnt, part);
        finalize_kernel<<<(NN * 3 + 255) / 256, 256, 0, stream>>>(part, (float*)d_out);
    } else {
        hipMemsetAsync(d_out, 0, (size_t)NN * 3 * sizeof(float), stream);
        edge_atomic_kernel<<<NE / 4 / 256, 256, 0, stream>>>(
            (const float4*)rij, (const float4*)vij, (const int4*)src, (const int4*)dst,
            q, (float*)d_out);
    }
}